// Round 7
// baseline (207.344 us; speedup 1.0000x reference)
//
#include <hip/hip_runtime.h>
#include <math.h>

#define NN 10000
#define EE 320000
#define PP 200000
#define WKP 10240   // padded K for W1T (zero-filled tail)

typedef __attribute__((ext_vector_type(8))) short bf8v;   // 8 bf16 (A/B frag)
typedef __attribute__((ext_vector_type(4))) float f4v;    // 4 f32  (C/D frag)

#define GLOAD_LDS16(gsrc, ldst)                                                        \
    __builtin_amdgcn_global_load_lds((const __attribute__((address_space(1))) void*)(gsrc), \
                                     (__attribute__((address_space(3))) void*)(ldst), 16, 0, 0)

// RTNE fp32 -> bf16 (finite inputs only)
__device__ __forceinline__ ushort f2bf(float f) {
    uint u = __float_as_uint(f);
    return (ushort)((u + 0x7fffu + ((u >> 16) & 1u)) >> 16);
}

// ---------------- degree / norm ----------------
__global__ void k_deg_count(const int* __restrict__ dst, int* __restrict__ degi) {
    int e = blockIdx.x * blockDim.x + threadIdx.x;
    if (e < EE) atomicAdd(&degi[dst[e]], 1);
}

__global__ void k_dinv(const int* __restrict__ degi, float* __restrict__ dinv) {
    int n = blockIdx.x * blockDim.x + threadIdx.x;
    if (n < NN) dinv[n] = rsqrtf((float)(degi[n] + 1));  // +1 self loop
}

// ---------------- W1 -> bf16 transposed [32][WKP], zero-padded ----------------
__global__ void k_wprep(const float* __restrict__ W1, ushort* __restrict__ w1t) {
    int t = blockIdx.x * blockDim.x + threadIdx.x;
    if (t >= 32 * WKP) return;
    int c = t / WKP, k = t - c * WKP;
    float v = (k < NN) ? W1[(long)k * 32 + c] : 0.f;
    w1t[t] = f2bf(v);
}

// ---------------- GEMM1: h1_pre = x @ W1 (10000x10000 @ 10000x32), bf16 MFMA ----------------
// BARRIER-FREE: each wave owns a private 3-deep LDS ring of its 32 x-rows
// (global_load_lds, source-preswizzled slots), staged 2 tiles ahead with a
// hand-placed s_waitcnt vmcnt(6) per tile (youngest 8 intrinsic VMEM ops are
// always tiles t+1,t+2 -> keeping <=6 guarantees tile t landed).
// B-fragments read directly from bf16 W1T in L2 (one 16B load per ct), no W LDS.
// Grid (79 row-blocks of 128, 16 K-splits of 640); 256 thr; wave w owns rows w*32..+32.
__global__ __launch_bounds__(256) void k_gemm1(const float* __restrict__ x,
                                               const ushort* __restrict__ w1t,
                                               const float* __restrict__ zp,
                                               float* __restrict__ h1_pre) {
    __shared__ __align__(16) float xs[4][3][32][32];   // [wave][buf][row][col] = 48 KB
    const int tid = threadIdx.x;
    const int lane = tid & 63;
    const int w = tid >> 6;            // wave id 0..3
    const int lr = lane >> 3;          // staging: row-within-8
    const int s = lane & 7;            // staging: 16B slot
    const int fl = lane & 15;          // fragment: row/col within 16
    const int khi = lane >> 4;         // fragment: k-group 0..3
    const int row0 = blockIdx.x * 128 + w * 32;   // this wave's first row
    const int k_begin = blockIdx.y * 640;
    const int k_end = min(NN, k_begin + 640);
    const int nt = (k_end - k_begin + 31) >> 5;   // 20 (or 13 for last split)
    const long NN2 = (long)NN * NN;

    f4v acc[2][2];
#pragma unroll
    for (int a = 0; a < 2; ++a)
#pragma unroll
        for (int b = 0; b < 2; ++b) acc[a][b] = (f4v){0.f, 0.f, 0.f, 0.f};

    // stage this wave's 32 rows x 32 cols for tile t into ring buffer `buf`
    auto stage_x = [&](int buf, int t) {
        const int k0 = k_begin + t * 32;
#pragma unroll
        for (int j = 0; j < 4; ++j) {
            int rl = j * 8 + lr;                              // wave-local row
            int c4 = s ^ (rl & 7);                            // pre-swizzled source slot
            long flat = (long)(row0 + rl) * NN + k0 + c4 * 4;
            const float* src = (flat + 4 <= NN2) ? (x + flat) : zp;
            GLOAD_LDS16(src, &xs[w][buf][j * 8][0]);
        }
    };
    // B fragments for tile t: col = ct*16+fl, k = khi*8..+8 (consecutive bf16 in W1T)
    auto wload = [&](int t, bf8v& b0, bf8v& b1) {
        const long kg = (long)k_begin + t * 32 + khi * 8;
        b0 = *(const bf8v*)(w1t + (long)(fl)      * WKP + kg);
        b1 = *(const bf8v*)(w1t + (long)(16 + fl) * WKP + kg);
    };
    auto compute = [&](int buf, bf8v b0, bf8v b1) {
#pragma unroll
        for (int rt = 0; rt < 2; ++rt) {
            const int rowl = rt * 16 + fl;
            const float4* xr = (const float4*)&xs[w][buf][rowl][0];
            float4 f0 = xr[(khi * 2)     ^ (rowl & 7)];       // k = khi*8 .. +4
            float4 f1 = xr[(khi * 2 + 1) ^ (rowl & 7)];       // k = khi*8+4 .. +8
            union { bf8v v; ushort u[8]; } a;
            a.u[0] = f2bf(f0.x); a.u[1] = f2bf(f0.y); a.u[2] = f2bf(f0.z); a.u[3] = f2bf(f0.w);
            a.u[4] = f2bf(f1.x); a.u[5] = f2bf(f1.y); a.u[6] = f2bf(f1.z); a.u[7] = f2bf(f1.w);
            acc[rt][0] = __builtin_amdgcn_mfma_f32_16x16x32_bf16(a.v, b0, acc[rt][0], 0, 0, 0);
            acc[rt][1] = __builtin_amdgcn_mfma_f32_16x16x32_bf16(a.v, b1, acc[rt][1], 0, 0, 0);
        }
    };

    // prologue: tiles 0,1 in flight; W-frags for tile 0 in regs
    bf8v wc0, wc1, wn0, wn1;
    stage_x(0, 0);
    stage_x(1, 1);
    wload(0, wc0, wc1);

    int buf = 0;
    for (int t = 0; t < nt; ++t) {
        if (t + 2 < nt) stage_x((buf + 2 == 3 ? buf - 1 : buf + 2), t + 2);
        if (t + 1 < nt) wload(t + 1, wn0, wn1);
        asm volatile("s_waitcnt vmcnt(6)" ::: "memory");      // tile t (and older) landed
        __builtin_amdgcn_sched_barrier(0);
        compute(buf, wc0, wc1);
        wc0 = wn0; wc1 = wn1;
        buf = (buf + 1 == 3) ? 0 : buf + 1;
    }

    // epilogue: C/D layout col=lane&15, row=(lane>>4)*4+reg (m89-verified)
#pragma unroll
    for (int rt = 0; rt < 2; ++rt) {
        const int gbase = row0 + rt * 16 + khi * 4;
#pragma unroll
        for (int ct = 0; ct < 2; ++ct) {
            const int col = ct * 16 + fl;
#pragma unroll
            for (int r = 0; r < 4; ++r) {
                const int g = gbase + r;
                if (g < NN) atomicAdd(&h1_pre[g * 32 + col], acc[rt][ct][r]);
            }
        }
    }
}

// ---------------- aggregation layer 1 (32 feats) ----------------
__global__ void k_selfinit1(const float* __restrict__ h1_pre, const float* __restrict__ dinv,
                            float* __restrict__ out1) {
    int t = blockIdx.x * blockDim.x + threadIdx.x;
    if (t < NN * 32) {
        int n = t >> 5;
        float di = dinv[n];
        out1[t] = di * di * h1_pre[t];
    }
}

__global__ void k_scatter1(const int* __restrict__ src, const int* __restrict__ dst,
                           const float* __restrict__ dinv, const float* __restrict__ h1_pre,
                           float* __restrict__ out1) {
    int t = blockIdx.x * blockDim.x + threadIdx.x;
    if (t >= EE * 32) return;
    int e = t >> 5, c = t & 31;
    int s = src[e], d = dst[e];
    float nrm = dinv[s] * dinv[d];
    atomicAdd(&out1[d * 32 + c], h1_pre[s * 32 + c] * nrm);
}

__global__ void k_bias_relu1(float* __restrict__ out1, const float* __restrict__ b1) {
    int t = blockIdx.x * blockDim.x + threadIdx.x;
    if (t < NN * 32) out1[t] = fmaxf(out1[t] + b1[t & 31], 0.f);
}

// ---------------- GEMM2: h2_pre = out1 @ W2  (10000x32 @ 32x16), fp32 ----------------
__global__ __launch_bounds__(256) void k_gemm2(const float* __restrict__ out1,
                                               const float* __restrict__ W2,
                                               float* __restrict__ h2_pre) {
    __shared__ float w2s[512];
    int tid = threadIdx.x;
    w2s[tid] = W2[tid & 511];
    if (tid < 256) w2s[256 + tid] = W2[256 + tid];
    __syncthreads();
    int c = tid & 15, yloc = tid >> 4;
    int n = blockIdx.x * 16 + yloc;
    if (n < NN) {
        float a = 0.f;
#pragma unroll
        for (int k = 0; k < 32; ++k) a += out1[n * 32 + k] * w2s[k * 16 + c];
        h2_pre[n * 16 + c] = a;
    }
}

// ---------------- aggregation layer 2 (16 feats) ----------------
__global__ void k_selfinit2(const float* __restrict__ h2_pre, const float* __restrict__ dinv,
                            float* __restrict__ out2) {
    int t = blockIdx.x * blockDim.x + threadIdx.x;
    if (t < NN * 16) {
        int n = t >> 4;
        float di = dinv[n];
        out2[t] = di * di * h2_pre[t];
    }
}

__global__ void k_scatter2(const int* __restrict__ src, const int* __restrict__ dst,
                           const float* __restrict__ dinv, const float* __restrict__ h2_pre,
                           float* __restrict__ out2) {
    int t = blockIdx.x * blockDim.x + threadIdx.x;
    if (t >= EE * 16) return;
    int e = t >> 4, c = t & 15;
    int s = src[e], d = dst[e];
    float nrm = dinv[s] * dinv[d];
    atomicAdd(&out2[d * 16 + c], h2_pre[s * 16 + c] * nrm);
}

// ---------------- final: per-node partial dots with Wfc ----------------
__global__ void k_final2(const float* __restrict__ out2, const float* __restrict__ b2,
                         const float* __restrict__ Wfc, float* __restrict__ s_arr,
                         float* __restrict__ t_arr) {
    int n = blockIdx.x * blockDim.x + threadIdx.x;
    if (n >= NN) return;
    float s = 0.f, t = 0.f;
#pragma unroll
    for (int c = 0; c < 16; ++c) {
        float v = out2[n * 16 + c] + b2[c];
        s += v * Wfc[c];
        t += v * Wfc[16 + c];
    }
    s_arr[n] = s;
    t_arr[n] = t;
}

// ---------------- pair scoring ----------------
__global__ void k_pairs(const int* __restrict__ pair, const float* __restrict__ s_arr,
                        const float* __restrict__ t_arr, const float* __restrict__ bfc,
                        float* __restrict__ out) {
    int p = blockIdx.x * blockDim.x + threadIdx.x;
    if (p >= PP) return;
    const int2 ab = ((const int2*)pair)[p];
    float z = s_arr[ab.x] + t_arr[ab.y] + bfc[0];
    out[p] = 1.f / (1.f + expf(-z));
}

extern "C" void kernel_launch(void* const* d_in, const int* in_sizes, int n_in,
                              void* d_out, int out_size, void* d_ws, size_t ws_size,
                              hipStream_t stream) {
    const float* x    = (const float*)d_in[0];
    const int*   edge = (const int*)d_in[1];   // [2][E]
    const int*   pair = (const int*)d_in[2];   // [P][2]
    const float* W1   = (const float*)d_in[3];
    const float* b1   = (const float*)d_in[4];
    const float* W2   = (const float*)d_in[5];
    const float* b2   = (const float*)d_in[6];
    const float* Wfc  = (const float*)d_in[7];
    const float* bfc  = (const float*)d_in[8];
    float* out = (float*)d_out;
    float* ws  = (float*)d_ws;

    const int* src = edge;
    const int* dst = edge + EE;

    // workspace layout (floats)
    int*    degi   = (int*)ws;            // N
    float*  dinv   = ws + NN;             // N
    float*  h1_pre = ws + 2 * NN;         // 32N
    float*  out1   = ws + 34 * NN;        // 32N
    float*  h2_pre = ws + 66 * NN;        // 16N
    float*  out2   = ws + 82 * NN;        // 16N
    float*  s_arr  = ws + 98 * NN;        // N
    float*  t_arr  = ws + 99 * NN;        // N
    float*  zp     = ws + 100 * NN;       // 256 floats zero page
    ushort* w1t    = (ushort*)(ws + 100 * NN + 256);   // 32*WKP bf16 = 640 KB

    hipMemsetAsync(degi, 0, NN * sizeof(int), stream);
    hipMemsetAsync(h1_pre, 0, NN * 32 * sizeof(float), stream);
    hipMemsetAsync(zp, 0, 1024, stream);

    k_deg_count<<<(EE + 255) / 256, 256, 0, stream>>>(dst, degi);
    k_dinv<<<(NN + 255) / 256, 256, 0, stream>>>(degi, dinv);
    k_wprep<<<(32 * WKP + 255) / 256, 256, 0, stream>>>(W1, w1t);

    k_gemm1<<<dim3(79, 16), 256, 0, stream>>>(x, w1t, zp, h1_pre);

    k_selfinit1<<<(NN * 32 + 255) / 256, 256, 0, stream>>>(h1_pre, dinv, out1);
    k_scatter1<<<(EE * 32 + 255) / 256, 256, 0, stream>>>(src, dst, dinv, h1_pre, out1);
    k_bias_relu1<<<(NN * 32 + 255) / 256, 256, 0, stream>>>(out1, b1);

    k_gemm2<<<(NN + 15) / 16, 256, 0, stream>>>(out1, W2, h2_pre);

    k_selfinit2<<<(NN * 16 + 255) / 256, 256, 0, stream>>>(h2_pre, dinv, out2);
    k_scatter2<<<(EE * 16 + 255) / 256, 256, 0, stream>>>(src, dst, dinv, h2_pre, out2);

    k_final2<<<(NN + 255) / 256, 256, 0, stream>>>(out2, b2, Wfc, s_arr, t_arr);
    k_pairs<<<(PP + 255) / 256, 256, 0, stream>>>(pair, s_arr, t_arr, bfc, out);
}

// Round 8
// 198.939 us; speedup vs baseline: 1.0422x; 1.0422x over previous
//
#include <hip/hip_runtime.h>
#include <math.h>

#define NN 10000
#define EE 320000
#define PP 200000
#define NTILES 320   // 10240/32 global K-tiles for W frag packing

typedef __attribute__((ext_vector_type(8))) short bf8v;   // 8 bf16 (A/B frag)
typedef __attribute__((ext_vector_type(4))) float f4v;    // 4 f32  (C/D frag)

#define GLOAD_LDS16(gsrc, ldst)                                                        \
    __builtin_amdgcn_global_load_lds((const __attribute__((address_space(1))) void*)(gsrc), \
                                     (__attribute__((address_space(3))) void*)(ldst), 16, 0, 0)

// RTNE fp32 -> bf16 (finite inputs only)
__device__ __forceinline__ ushort f2bf(float f) {
    uint u = __float_as_uint(f);
    return (ushort)((u + 0x7fffu + ((u >> 16) & 1u)) >> 16);
}

// ---------------- degree / norm ----------------
__global__ void k_deg_count(const int* __restrict__ dst, int* __restrict__ degi) {
    int e = blockIdx.x * blockDim.x + threadIdx.x;
    if (e < EE) atomicAdd(&degi[dst[e]], 1);
}

__global__ void k_dinv(const int* __restrict__ degi, float* __restrict__ dinv) {
    int n = blockIdx.x * blockDim.x + threadIdx.x;
    if (n < NN) dinv[n] = rsqrtf((float)(degi[n] + 1));  // +1 self loop
}

// ---------------- W1 -> bf16 in MFMA-fragment order ----------------
// w1t_frag[((g*2+ct)*64 + lane)*8 + e] = W1[k][col], k=g*32+(lane>>4)*8+e,
// col=ct*16+(lane&15); zero for k>=NN. 320*2*64*8 bf16 = 655 KB.
__global__ void k_wprep(const float* __restrict__ W1, ushort* __restrict__ wf) {
    int t = blockIdx.x * blockDim.x + threadIdx.x;
    if (t >= NTILES * 2 * 64 * 8) return;
    int e = t & 7, lane = (t >> 3) & 63, ct = (t >> 9) & 1, g = t >> 10;
    int col = ct * 16 + (lane & 15);
    int k = g * 32 + (lane >> 4) * 8 + e;
    wf[t] = (k < NN) ? f2bf(W1[(long)k * 32 + col]) : (ushort)0;
}

// ---------------- GEMM1: h1_pre = x @ W1 (10000x10000 @ 10000x32), bf16 MFMA ----------------
// Fully decoupled per-wave stream: depth-2 private LDS ring holding x-tile (fp32,
// source-preswizzled) + W B-frags (bf16, fragment-order pack). Loop body:
// issue 6 global_load_lds for tile t+1 -> s_waitcnt vmcnt(6) (FIFO: tile t landed,
// t+1 in flight) -> sched_barrier -> compute. NO barriers, NO carried VMEM registers,
// NO compiler-forced drains. Grid (79 row-panels of 128, 16 K-splits); 4 waves/block.
__global__ __launch_bounds__(256) void k_gemm1(const float* __restrict__ x,
                                               const ushort* __restrict__ wf,
                                               const float* __restrict__ zp,
                                               float* __restrict__ h1_pre) {
    __shared__ __align__(16) float  xs[4][2][32][32];   // 32 KB
    __shared__ __align__(16) ushort ws[4][2][1024];     // 16 KB
    const int tid = threadIdx.x;
    const int lane = tid & 63;
    const int w = tid >> 6;            // wave id 0..3
    const int lr = lane >> 3;          // staging: row-within-8
    const int s = lane & 7;            // staging: 16B slot
    const int fl = lane & 15;          // fragment: row/col within 16
    const int khi = lane >> 4;         // fragment: k-group 0..3
    const int row0 = blockIdx.x * 128 + w * 32;   // this wave's first row
    const int k_begin = blockIdx.y * 640;
    const int k_end = min(NN, k_begin + 640);
    const int g0 = blockIdx.y * 20;               // global tile index base
    const int nt = (k_end - k_begin + 31) >> 5;   // 20 (13 for last split)
    const long NN2 = (long)NN * NN;

    f4v acc[2][2];
#pragma unroll
    for (int a = 0; a < 2; ++a)
#pragma unroll
        for (int b = 0; b < 2; ++b) acc[a][b] = (f4v){0.f, 0.f, 0.f, 0.f};

    // stage tile t (6 gload_lds: 4 x + 2 W-frag) into ring buffer `buf`
    auto stage = [&](int buf, int t) {
        const int k0 = k_begin + t * 32;
#pragma unroll
        for (int j = 0; j < 4; ++j) {
            int rl = j * 8 + lr;                              // wave-local row
            int c4 = s ^ (rl & 7);                            // pre-swizzled source slot
            long flat = (long)(row0 + rl) * NN + k0 + c4 * 4;
            const float* src = (flat + 4 <= NN2) ? (x + flat) : zp;
            GLOAD_LDS16(src, &xs[w][buf][j * 8][0]);
        }
        const int g = g0 + t;
#pragma unroll
        for (int ct = 0; ct < 2; ++ct)
            GLOAD_LDS16(wf + ((long)(g * 2 + ct) * 64 + lane) * 8, &ws[w][buf][ct * 512]);
    };
    auto compute = [&](int buf) {
        bf8v b0 = *(const bf8v*)&ws[w][buf][lane * 8];          // linear lane*16B: bank-free
        bf8v b1 = *(const bf8v*)&ws[w][buf][512 + lane * 8];
#pragma unroll
        for (int rt = 0; rt < 2; ++rt) {
            const int rowl = rt * 16 + fl;
            const float4* xr = (const float4*)&xs[w][buf][rowl][0];
            float4 f0 = xr[(khi * 2)     ^ (rowl & 7)];       // k = khi*8 .. +4
            float4 f1 = xr[(khi * 2 + 1) ^ (rowl & 7)];       // k = khi*8+4 .. +8
            union { bf8v v; ushort u[8]; } a;
            a.u[0] = f2bf(f0.x); a.u[1] = f2bf(f0.y); a.u[2] = f2bf(f0.z); a.u[3] = f2bf(f0.w);
            a.u[4] = f2bf(f1.x); a.u[5] = f2bf(f1.y); a.u[6] = f2bf(f1.z); a.u[7] = f2bf(f1.w);
            acc[rt][0] = __builtin_amdgcn_mfma_f32_16x16x32_bf16(a.v, b0, acc[rt][0], 0, 0, 0);
            acc[rt][1] = __builtin_amdgcn_mfma_f32_16x16x32_bf16(a.v, b1, acc[rt][1], 0, 0, 0);
        }
    };

    stage(0, 0);
    int buf = 0;
    for (int t = 0; t < nt; ++t) {
        if (t + 1 < nt) {
            stage(buf ^ 1, t + 1);
            asm volatile("s_waitcnt vmcnt(6)" ::: "memory");  // tile t landed; t+1 in flight
        } else {
            asm volatile("s_waitcnt vmcnt(0)" ::: "memory");
        }
        __builtin_amdgcn_sched_barrier(0);
        compute(buf);
        buf ^= 1;
    }

    // epilogue: C/D layout col=lane&15, row=(lane>>4)*4+reg (m89-verified)
#pragma unroll
    for (int rt = 0; rt < 2; ++rt) {
        const int gbase = row0 + rt * 16 + khi * 4;
#pragma unroll
        for (int ct = 0; ct < 2; ++ct) {
            const int col = ct * 16 + fl;
#pragma unroll
            for (int r = 0; r < 4; ++r) {
                const int g = gbase + r;
                if (g < NN) atomicAdd(&h1_pre[g * 32 + col], acc[rt][ct][r]);
            }
        }
    }
}

// ---------------- aggregation layer 1 (32 feats) ----------------
__global__ void k_selfinit1(const float* __restrict__ h1_pre, const float* __restrict__ dinv,
                            float* __restrict__ out1) {
    int t = blockIdx.x * blockDim.x + threadIdx.x;
    if (t < NN * 32) {
        int n = t >> 5;
        float di = dinv[n];
        out1[t] = di * di * h1_pre[t];
    }
}

__global__ void k_scatter1(const int* __restrict__ src, const int* __restrict__ dst,
                           const float* __restrict__ dinv, const float* __restrict__ h1_pre,
                           float* __restrict__ out1) {
    int t = blockIdx.x * blockDim.x + threadIdx.x;
    if (t >= EE * 32) return;
    int e = t >> 5, c = t & 31;
    int s = src[e], d = dst[e];
    float nrm = dinv[s] * dinv[d];
    atomicAdd(&out1[d * 32 + c], h1_pre[s * 32 + c] * nrm);
}

__global__ void k_bias_relu1(float* __restrict__ out1, const float* __restrict__ b1) {
    int t = blockIdx.x * blockDim.x + threadIdx.x;
    if (t < NN * 32) out1[t] = fmaxf(out1[t] + b1[t & 31], 0.f);
}

// ---------------- GEMM2: h2_pre = out1 @ W2  (10000x32 @ 32x16), fp32 ----------------
__global__ __launch_bounds__(256) void k_gemm2(const float* __restrict__ out1,
                                               const float* __restrict__ W2,
                                               float* __restrict__ h2_pre) {
    __shared__ float w2s[512];
    int tid = threadIdx.x;
    w2s[tid] = W2[tid & 511];
    if (tid < 256) w2s[256 + tid] = W2[256 + tid];
    __syncthreads();
    int c = tid & 15, yloc = tid >> 4;
    int n = blockIdx.x * 16 + yloc;
    if (n < NN) {
        float a = 0.f;
#pragma unroll
        for (int k = 0; k < 32; ++k) a += out1[n * 32 + k] * w2s[k * 16 + c];
        h2_pre[n * 16 + c] = a;
    }
}

// ---------------- aggregation layer 2 (16 feats) ----------------
__global__ void k_selfinit2(const float* __restrict__ h2_pre, const float* __restrict__ dinv,
                            float* __restrict__ out2) {
    int t = blockIdx.x * blockDim.x + threadIdx.x;
    if (t < NN * 16) {
        int n = t >> 4;
        float di = dinv[n];
        out2[t] = di * di * h2_pre[t];
    }
}

__global__ void k_scatter2(const int* __restrict__ src, const int* __restrict__ dst,
                           const float* __restrict__ dinv, const float* __restrict__ h2_pre,
                           float* __restrict__ out2) {
    int t = blockIdx.x * blockDim.x + threadIdx.x;
    if (t >= EE * 16) return;
    int e = t >> 4, c = t & 15;
    int s = src[e], d = dst[e];
    float nrm = dinv[s] * dinv[d];
    atomicAdd(&out2[d * 16 + c], h2_pre[s * 16 + c] * nrm);
}

// ---------------- final: per-node partial dots with Wfc ----------------
__global__ void k_final2(const float* __restrict__ out2, const float* __restrict__ b2,
                         const float* __restrict__ Wfc, float* __restrict__ s_arr,
                         float* __restrict__ t_arr) {
    int n = blockIdx.x * blockDim.x + threadIdx.x;
    if (n >= NN) return;
    float s = 0.f, t = 0.f;
#pragma unroll
    for (int c = 0; c < 16; ++c) {
        float v = out2[n * 16 + c] + b2[c];
        s += v * Wfc[c];
        t += v * Wfc[16 + c];
    }
    s_arr[n] = s;
    t_arr[n] = t;
}

// ---------------- pair scoring ----------------
__global__ void k_pairs(const int* __restrict__ pair, const float* __restrict__ s_arr,
                        const float* __restrict__ t_arr, const float* __restrict__ bfc,
                        float* __restrict__ out) {
    int p = blockIdx.x * blockDim.x + threadIdx.x;
    if (p >= PP) return;
    const int2 ab = ((const int2*)pair)[p];
    float z = s_arr[ab.x] + t_arr[ab.y] + bfc[0];
    out[p] = 1.f / (1.f + expf(-z));
}

extern "C" void kernel_launch(void* const* d_in, const int* in_sizes, int n_in,
                              void* d_out, int out_size, void* d_ws, size_t ws_size,
                              hipStream_t stream) {
    const float* x    = (const float*)d_in[0];
    const int*   edge = (const int*)d_in[1];   // [2][E]
    const int*   pair = (const int*)d_in[2];   // [P][2]
    const float* W1   = (const float*)d_in[3];
    const float* b1   = (const float*)d_in[4];
    const float* W2   = (const float*)d_in[5];
    const float* b2   = (const float*)d_in[6];
    const float* Wfc  = (const float*)d_in[7];
    const float* bfc  = (const float*)d_in[8];
    float* out = (float*)d_out;
    float* ws  = (float*)d_ws;

    const int* src = edge;
    const int* dst = edge + EE;

    // workspace layout (floats)
    int*    degi   = (int*)ws;            // N
    float*  dinv   = ws + NN;             // N
    float*  h1_pre = ws + 2 * NN;         // 32N
    float*  out1   = ws + 34 * NN;        // 32N
    float*  h2_pre = ws + 66 * NN;        // 16N
    float*  out2   = ws + 82 * NN;        // 16N
    float*  s_arr  = ws + 98 * NN;        // N
    float*  t_arr  = ws + 99 * NN;        // N
    float*  zp     = ws + 100 * NN;       // 256 floats zero page
    ushort* w1f    = (ushort*)(ws + 100 * NN + 256);   // 320*2*64*8 bf16 = 655 KB

    hipMemsetAsync(degi, 0, NN * sizeof(int), stream);
    hipMemsetAsync(h1_pre, 0, NN * 32 * sizeof(float), stream);
    hipMemsetAsync(zp, 0, 1024, stream);

    k_deg_count<<<(EE + 255) / 256, 256, 0, stream>>>(dst, degi);
    k_dinv<<<(NN + 255) / 256, 256, 0, stream>>>(degi, dinv);
    k_wprep<<<(NTILES * 2 * 64 * 8 + 255) / 256, 256, 0, stream>>>(W1, w1f);

    k_gemm1<<<dim3(79, 16), 256, 0, stream>>>(x, w1f, zp, h1_pre);

    k_selfinit1<<<(NN * 32 + 255) / 256, 256, 0, stream>>>(h1_pre, dinv, out1);
    k_scatter1<<<(EE * 32 + 255) / 256, 256, 0, stream>>>(src, dst, dinv, h1_pre, out1);
    k_bias_relu1<<<(NN * 32 + 255) / 256, 256, 0, stream>>>(out1, b1);

    k_gemm2<<<(NN + 15) / 16, 256, 0, stream>>>(out1, W2, h2_pre);

    k_selfinit2<<<(NN * 16 + 255) / 256, 256, 0, stream>>>(h2_pre, dinv, out2);
    k_scatter2<<<(EE * 16 + 255) / 256, 256, 0, stream>>>(src, dst, dinv, h2_pre, out2);

    k_final2<<<(NN + 255) / 256, 256, 0, stream>>>(out2, b2, Wfc, s_arr, t_arr);
    k_pairs<<<(PP + 255) / 256, 256, 0, stream>>>(pair, s_arr, t_arr, bfc, out);
}